// Round 14
// baseline (240.550 us; speedup 1.0000x reference)
//
#include <hip/hip_runtime.h>
#include <hip/hip_fp16.h>

// B=8, N=1024, E=512, H=8, D=64
// ws (f16): X16, A2, WQ, W2, QP/KP/WP packed A/B-frag, VP packed, OUTP[4] f16
// kdots v4: ktile-PAIR scatter (dest 32x128) -- rel-shift raw windows amortize
//   (159/128 vs 95/64), A-window skips 3rd row-fragment, barriers halved
//   (2 per 128-col pair). sd[8][32][128] = 64KB, col-XOR swizzle (row&7)<<3.
// kproj: reg-staging (gls serialized stage/compute: r12). (512,4): 128-VGPR cap.

typedef _Float16 f16;
typedef f16 f16x4 __attribute__((ext_vector_type(4)));
typedef f16 f16x8 __attribute__((ext_vector_type(8)));
typedef float f32x4 __attribute__((ext_vector_type(4)));

#define MFMA16(a,b,c) __builtin_amdgcn_mfma_f32_16x16x32_f16((a),(b),(c),0,0,0)

static __device__ __forceinline__ size_t qpidx(int bh, int q, int d) {
  return ((((size_t)bh * 64 + (q >> 4)) * 2 + (d >> 5)) * 64 +
          ((q & 15) + (((d >> 3) & 3) << 4))) * 8 + (d & 7);
}
static __device__ __forceinline__ size_t vpidx(int bh, int d, int j) {
  return ((((size_t)bh * 4 + (d >> 4)) * 32 + (j >> 5)) * 64 +
          ((d & 15) + (((j >> 3) & 3) << 4))) * 8 + (j & 7);
}

// ---------------- Kernel 0: prep (convert + concat + transpose weights) -----
__global__ __launch_bounds__(256) void kprep(
    const float* __restrict__ x, const float* __restrict__ rt, const float* __restrict__ rc,
    const float* __restrict__ wqkv, const float* __restrict__ wkrt, const float* __restrict__ wkrc,
    f16* __restrict__ X16, f16* __restrict__ A2, f16* __restrict__ WQ, f16* __restrict__ W2)
{
  const int t = threadIdx.x, gx = blockIdx.x, mode = blockIdx.y;
  if (mode <= 2) {
    const size_t id = (size_t)gx * 256 + t;
    const float* src = (mode == 0) ? x : (mode == 1) ? rt : rc;
    float4 v0 = *(const float4*)&src[id * 8];
    float4 v1 = *(const float4*)&src[id * 8 + 4];
    f16x8 o = {(f16)v0.x, (f16)v0.y, (f16)v0.z, (f16)v0.w,
               (f16)v1.x, (f16)v1.y, (f16)v1.z, (f16)v1.w};
    if (mode == 0) *(f16x8*)&X16[id * 8] = o;
    else {
      const int mrow = (int)(id >> 6), cc = (int)(id & 63);
      *(f16x8*)&A2[(size_t)mrow * 1024 + (mode == 2 ? 512 : 0) + cc * 8] = o;
    }
  } else if (mode == 3) {
    if (gx >= 384) return;
    const int c = gx & 63, n = (gx >> 6) * 256 + t;
    f16x8 o;
    #pragma unroll
    for (int e = 0; e < 8; ++e) o[e] = (f16)wqkv[(size_t)(c * 8 + e) * 1536 + n];
    *(f16x8*)&WQ[(size_t)n * 512 + c * 8] = o;
  } else {
    if (gx >= 128) return;
    const int c = gx & 63, n = (gx >> 6) * 256 + t;
    const float* src = (mode == 4) ? wkrt : wkrc;
    f16x8 o;
    #pragma unroll
    for (int e = 0; e < 8; ++e) o[e] = (f16)src[(size_t)(c * 8 + e) * 512 + n];
    *(f16x8*)&W2[(size_t)n * 1024 + (mode == 5 ? 512 : 0) + c * 8] = o;
  }
}

// ---------------- Kernel A: projections (128x128 tile, BK=64, swizzled LDS) --
__global__ __launch_bounds__(256) void kproj(
    const f16* __restrict__ X16, const f16* __restrict__ A2,
    const f16* __restrict__ WQ, const f16* __restrict__ W2,
    const float* __restrict__ bias_te,
    f16* __restrict__ QP, f16* __restrict__ KP, f16* __restrict__ VP, f16* __restrict__ WP)
{
  __shared__ f16 As[128 * 64];
  __shared__ f16 Bs[128 * 64];
  const int t = threadIdx.x, l = t & 63, w = t >> 6;
  const int wr = w >> 1, wc = w & 1;
  const int lin = blockIdx.x + 64 * blockIdx.y;
  const int mchunk = lin & 7;
  const int rem = lin >> 3;
  const int m0 = (mchunk * 8 + (rem & 7)) * 128;
  const int y = rem >> 3;
  const int mode = y >> 2;
  const bool wrs = (mode == 3);
  const f16* Asrc = wrs ? A2 : X16;
  const int lda = wrs ? 1024 : 512;
  const int K = wrs ? 1024 : 512;
  const f16* Bsrc = wrs ? (W2 + (size_t)((y - 12) * 128) * 1024)
                        : (WQ + (size_t)(y * 128) * 512);
  const int ldb = wrs ? 1024 : 512;

  f32x4 acc[4][4] = {};
  for (int k0 = 0; k0 < K; k0 += 64) {
    __syncthreads();
    #pragma unroll
    for (int rep = 0; rep < 4; ++rep) {
      const int idx = rep * 256 + t;
      const int row = idx >> 3, kb = idx & 7;
      const int slot = (kb ^ (row & 7)) << 3;
      f16x8 va = *(const f16x8*)&Asrc[(size_t)(m0 + row) * lda + k0 + kb * 8];
      *(f16x8*)&As[row * 64 + slot] = va;
      f16x8 vb = *(const f16x8*)&Bsrc[(size_t)row * ldb + k0 + kb * 8];
      *(f16x8*)&Bs[row * 64 + slot] = vb;
    }
    __syncthreads();
    #pragma unroll
    for (int kc = 0; kc < 2; ++kc) {
      f16x8 af[4], bf[4];
      const int kb = kc * 4 + (l >> 4);
      #pragma unroll
      for (int mb = 0; mb < 4; ++mb) {
        const int r = wr * 64 + mb * 16 + (l & 15);
        af[mb] = *(const f16x8*)&As[r * 64 + ((kb ^ (r & 7)) << 3)];
      }
      #pragma unroll
      for (int nb = 0; nb < 4; ++nb) {
        const int r = wc * 64 + nb * 16 + (l & 15);
        bf[nb] = *(const f16x8*)&Bs[r * 64 + ((kb ^ (r & 7)) << 3)];
      }
      #pragma unroll
      for (int mb = 0; mb < 4; ++mb)
      #pragma unroll
      for (int nb = 0; nb < 4; ++nb)
        acc[mb][nb] = MFMA16(af[mb], bf[nb], acc[mb][nb]);
    }
  }
  #pragma unroll
  for (int mb = 0; mb < 4; ++mb)
  #pragma unroll
  for (int nb = 0; nb < 4; ++nb) {
    const int loc = wc * 64 + nb * 16 + (l & 15);
    const int c = (y & 3) * 128 + loc;
    const int hh = c >> 6, d = c & 63;
    const float badd = (mode == 0) ? bias_te[c] : 0.f;
    f32x4 a = acc[mb][nb];
    #pragma unroll
    for (int r = 0; r < 4; ++r) {
      const int m = m0 + wr * 64 + mb * 16 + (l >> 4) * 4 + r;
      const int bb = m >> 10, tn = m & 1023;
      const int bh = bb * 8 + hh;
      const float v = a[r] + badd;
      if (mode == 0)      QP[qpidx(bh, tn, d)] = (f16)v;
      else if (mode == 1) KP[qpidx(bh, tn, d)] = (f16)v;
      else if (mode == 2) VP[vpidx(bh, d, tn)] = (f16)v;
      else                WP[qpidx(bh, tn, d)] = (f16)(0.5f * v);  // fold BD*0.5
    }
  }
}

// ---- Kernel C: fused rel-shift + dots + h-softmax + attn write + PV --------
// 1024 blocks; 512 threads, wave = head. XCD swizzle: lin%8 == b.
// Per PAIR (128 k-cols): rawT scatter-STORE -> AC f16x4 RMW (hole->AC) ->
// [sync] softmax (2 passes) [sync] PV. 2 barriers per 128 cols.
__global__ __launch_bounds__(512, 4) void kdots(
    const f16* __restrict__ QP, const f16* __restrict__ KP,
    const f16* __restrict__ WP, const f16* __restrict__ VP,
    float* __restrict__ attn_out, f16* __restrict__ OUTP)
{
  __shared__ f16 sd[8][32][128];     // col-XOR swizzle: k ^= (row&7)<<3
  const int t = threadIdx.x, l = t & 63, h = t >> 6;
  const int lin = blockIdx.x + 4 * blockIdx.y + 128 * blockIdx.z;
  const int b = lin & 7;             // XCD j owns batch j
  const int rem = lin >> 3;
  const int kg = rem & 3;
  const int q0 = (rem >> 2) * 32;
  const int bh = b * 8 + h;
  const f16x8* QP8 = (const f16x8*)QP;
  const f16x8* KP8 = (const f16x8*)KP;
  const f16x8* WP8 = (const f16x8*)WP;
  const f16x8* VP8 = (const f16x8*)VP;
  const int qrow = (l >> 4) * 4;
  // Q fragments: rows q0..q0+47 (3rd only feeds region B row q0+32)
  f16x8 aq[3][2];
  #pragma unroll
  for (int mb = 0; mb < 3; ++mb)
  #pragma unroll
  for (int kc = 0; kc < 2; ++kc)
    aq[mb][kc] = QP8[((size_t)(bh * 64 + (q0 >> 4) + mb) * 2 + kc) * 64 + l];

  f32x4 oacc[2][4] = {};   // PV accumulator across the 2 pairs

  #pragma unroll 1
  for (int pr = 0; pr < 2; ++pr) {
    const int pk0 = kg * 256 + pr * 128;
    const int u = pk0 - q0;
    // ---- rawT = (0.5*WRS) . QB^T; scatter-STORE into 32x128 window.
    auto rawblockT = [&](int jb, bool q2) {
      f32x4 racc[3] = {};
      #pragma unroll
      for (int kc = 0; kc < 2; ++kc) {
        f16x8 wf = WP8[((size_t)(bh * 64 + jb) * 2 + kc) * 64 + l];
        racc[0] = MFMA16(wf, aq[0][kc], racc[0]);
        racc[1] = MFMA16(wf, aq[1][kc], racc[1]);
        if (q2) racc[2] = MFMA16(wf, aq[2][kc], racc[2]);
      }
      #pragma unroll
      for (int qb = 0; qb < 3; ++qb) {
        if (qb == 2 && !q2) break;
        const int qloc = qb * 16 + (l & 15);
        const int base = (q0 + qloc) + (jb * 16 + qrow) - 1023;  // kA at r=0
        #pragma unroll
        for (int r = 0; r < 4; ++r) {
          int kd = base + r;
          int row = qloc;
          if (kd < pk0) { kd += 1024; row -= 1; }    // region B form
          const unsigned col = (unsigned)(kd - pk0);
          if ((unsigned)row < 32u && col < 128u)
            sd[h][row][col ^ ((row & 7) << 3)] = (f16)racc[qb][r];
        }
      }
    };
    {  // B-window: jj in [u-33, u+126]; needs 3rd row-fragment
      const int bhi_e = (u + 126 > 1023) ? 1023 : u + 126;
      if (bhi_e >= 0) {
        const int blo_e = u - 33;
        const int blo = (blo_e < 0 ? 0 : blo_e) >> 4, bhi = bhi_e >> 4;
        for (int jb = blo; jb <= bhi; ++jb) rawblockT(jb, true);
      }
    }
    if (u <= 31) {  // A-window: jj in [992+u, 1150+u]; rows <= q0+31 only
      const int alo_e = 992 + u;
      const int ahi_e = (1150 + u > 1023) ? 1023 : 1150 + u;
      const int alo = (alo_e < 0 ? 0 : alo_e) >> 4, ahi = ahi_e >> 4;
      for (int jb = alo; jb <= ahi; ++jb) rawblockT(jb, false);
    }
    // ---- AC = K . QB^T in two 64-col subtiles; f16x4 RMW-add (hole->AC) ----
    #pragma unroll
    for (int sub = 0; sub < 2; ++sub) {
      f32x4 acc[4][2] = {};
      const int kk = (pk0 >> 4) + sub * 4;
      #pragma unroll
      for (int kc = 0; kc < 2; ++kc)
      #pragma unroll
      for (int kb = 0; kb < 4; ++kb) {
        f16x8 kf = KP8[((size_t)(bh * 64 + kk + kb) * 2 + kc) * 64 + l];
        acc[kb][0] = MFMA16(kf, aq[0][kc], acc[kb][0]);
        acc[kb][1] = MFMA16(kf, aq[1][kc], acc[kb][1]);
      }
      #pragma unroll
      for (int kb = 0; kb < 4; ++kb)
      #pragma unroll
      for (int qb = 0; qb < 2; ++qb) {
        const int qloc = qb * 16 + (l & 15);
        const int kbase = sub * 64 + kb * 16 + qrow;
        const int hol = (q0 + qloc + 1) - (pk0 + kbase);   // hole e in [0,3]?
        f16* p = &sd[h][qloc][kbase ^ ((qloc & 7) << 3)];
        f16x4 cur = *(const f16x4*)p;
        f16x4 res;
        #pragma unroll
        for (int e = 0; e < 4; ++e) {
          const float rv = (e == hol) ? 0.f : (float)cur[e];
          res[e] = (f16)(rv + acc[kb][qb][e]);
        }
        *(f16x4*)p = res;
      }
    }
    __syncthreads();
    // ---- softmax over heads (2 passes of 16 rows) + attn nt-write + P ----
    #pragma unroll
    for (int pass = 0; pass < 2; ++pass) {
      const int idx = pass * 2048 + t * 4;
      const int q = idx >> 7, k = idx & 127;
      const int ks = k ^ ((q & 7) << 3);
      float dv[8][4];
      #pragma unroll
      for (int hh = 0; hh < 8; ++hh) {
        f16x4 v = *(const f16x4*)&sd[hh][q][ks];
        dv[hh][0] = (float)v[0]; dv[hh][1] = (float)v[1];
        dv[hh][2] = (float)v[2]; dv[hh][3] = (float)v[3];
      }
      #pragma unroll
      for (int e = 0; e < 4; ++e) {
        float m = dv[0][e];
        #pragma unroll
        for (int hh = 1; hh < 8; ++hh) m = fmaxf(m, dv[hh][e]);
        float ssum = 0.f;
        #pragma unroll
        for (int hh = 0; hh < 8; ++hh) { float a = __expf(dv[hh][e] - m); dv[hh][e] = a; ssum += a; }
        float rinv = 1.f / ssum;
        #pragma unroll
        for (int hh = 0; hh < 8; ++hh) dv[hh][e] *= rinv;
      }
      const size_t qg = q0 + q;
      #pragma unroll
      for (int hh = 0; hh < 8; ++hh) {
        f32x4* dst = (f32x4*)&attn_out[((size_t)(b * 8 + hh) * 1024 + qg) * 1024 + pk0 + k];
        __builtin_nontemporal_store(f32x4{dv[hh][0], dv[hh][1], dv[hh][2], dv[hh][3]}, dst);
        *(f16x4*)&sd[hh][q][ks] =
            f16x4{(f16)dv[hh][0], (f16)dv[hh][1], (f16)dv[hh][2], (f16)dv[hh][3]};
      }
    }
    __syncthreads();
    // ---- PV: oacc[q,d] += P[q,j] * V[j,d] over 128 j ----
    #pragma unroll
    for (int kc = 0; kc < 4; ++kc) {
      f16x8 pa[2];
      #pragma unroll
      for (int mb = 0; mb < 2; ++mb) {
        const int qq = mb * 16 + (l & 15);
        const int jj = kc * 32 + (l >> 4) * 8;
        pa[mb] = *(const f16x8*)&sd[h][qq][jj ^ ((qq & 7) << 3)];
      }
      #pragma unroll
      for (int nb = 0; nb < 4; ++nb) {
        f16x8 vb = VP8[(((size_t)bh * 4 + nb) * 32 + (pk0 >> 5) + kc) * 64 + l];
        #pragma unroll
        for (int mb = 0; mb < 2; ++mb)
          oacc[mb][nb] = MFMA16(pa[mb], vb, oacc[mb][nb]);
      }
    }
  }
  // ---- write PV partial (f16): OUTP[kg][b*1024+q][h*64+d] ----
  f16* op = OUTP + ((size_t)kg * 8192 + (size_t)b * 1024) * 512;
  #pragma unroll
  for (int mb = 0; mb < 2; ++mb)
  #pragma unroll
  for (int nb = 0; nb < 4; ++nb)
  #pragma unroll
  for (int r = 0; r < 4; ++r) {
    const int qg = q0 + mb * 16 + qrow + r;
    const int dd = nb * 16 + (l & 15);
    op[(size_t)qg * 512 + h * 64 + dd] = (f16)oacc[mb][nb][r];
  }
}

// ---------------- Kernel D: out = (sum_p OUTP[p]) @ w_out + b_out ----------
__global__ __launch_bounds__(256) void kout(
    const f16* __restrict__ OUTP, const float* __restrict__ w_out,
    const float* __restrict__ b_out, float* __restrict__ out)
{
  __shared__ f16 a_s[128][36];
  __shared__ f16 b_s[64][36];
  const int t = threadIdx.x, l = t & 63, w = t >> 6;
  const int m0 = blockIdx.x * 128;
  const int c0 = blockIdx.y * 64;
  f32x4 acc[2][4] = {};
  for (int k0 = 0; k0 < 512; k0 += 32) {
    __syncthreads();
    #pragma unroll
    for (int rep = 0; rep < 2; ++rep) {       // A: sum 4 f16 partials -> f16
      const int s = rep * 256 + t;
      const int r = s >> 2, c = (s & 3) * 8;
      const size_t off = (size_t)(m0 + r) * 512 + k0 + c;
      f16x8 p0 = *(const f16x8*)&OUTP[off];
      f16x8 p1 = *(const f16x8*)&OUTP[off + 4194304];
      f16x8 p2 = *(const f16x8*)&OUTP[off + 8388608];
      f16x8 p3 = *(const f16x8*)&OUTP[off + 12582912];
      f16x4 lo, hi;
      #pragma unroll
      for (int e = 0; e < 4; ++e) {
        lo[e] = (f16)((float)p0[e] + (float)p1[e] + (float)p2[e] + (float)p3[e]);
        hi[e] = (f16)((float)p0[e+4] + (float)p1[e+4] + (float)p2[e+4] + (float)p3[e+4]);
      }
      *(f16x4*)&a_s[r][c]     = lo;
      *(f16x4*)&a_s[r][c + 4] = hi;
    }
    #pragma unroll
    for (int rep = 0; rep < 2; ++rep) {
      int idx = rep * 1024 + t * 4;
      int kr = idx >> 6, c = idx & 63;
      float4 v = *(const float4*)&w_out[(size_t)(k0 + kr) * 512 + c0 + c];
      b_s[c + 0][kr] = (f16)v.x; b_s[c + 1][kr] = (f16)v.y;
      b_s[c + 2][kr] = (f16)v.z; b_s[c + 3][kr] = (f16)v.w;
    }
    __syncthreads();
    const int kc = (l >> 4) * 8;
    f16x8 af[2];
    #pragma unroll
    for (int mb = 0; mb < 2; ++mb) {
      int r = w * 32 + mb * 16 + (l & 15);
      af[mb] = __builtin_shufflevector(*(const f16x4*)&a_s[r][kc], *(const f16x4*)&a_s[r][kc + 4],
                                       0, 1, 2, 3, 4, 5, 6, 7);
    }
    #pragma unroll
    for (int nb = 0; nb < 4; ++nb) {
      int cc = nb * 16 + (l & 15);
      f16x8 bf = __builtin_shufflevector(*(const f16x4*)&b_s[cc][kc], *(const f16x4*)&b_s[cc][kc + 4],
                                         0, 1, 2, 3, 4, 5, 6, 7);
      #pragma unroll
      for (int mb = 0; mb < 2; ++mb)
        acc[mb][nb] = MFMA16(af[mb], bf, acc[mb][nb]);
    }
  }
  #pragma unroll
  for (int mb = 0; mb < 2; ++mb)
  #pragma unroll
  for (int nb = 0; nb < 4; ++nb) {
    const int cg = c0 + nb * 16 + (l & 15);
    const float bb = b_out[cg];
    #pragma unroll
    for (int r = 0; r < 4; ++r) {
      const int m = m0 + w * 32 + mb * 16 + (l >> 4) * 4 + r;
      out[(size_t)m * 512 + cg] = acc[mb][nb][r] + bb;
    }
  }
}

extern "C" void kernel_launch(void* const* d_in, const int* in_sizes, int n_in,
                              void* d_out, int out_size, void* d_ws, size_t ws_size,
                              hipStream_t stream) {
  const float* x       = (const float*)d_in[0];
  const float* rt      = (const float*)d_in[1];
  const float* rc      = (const float*)d_in[2];
  const float* bias_te = (const float*)d_in[3];
  const float* w_qkv   = (const float*)d_in[7];
  const float* w_kr_t  = (const float*)d_in[8];
  const float* w_kr_c  = (const float*)d_in[9];
  const float* w_out   = (const float*)d_in[10];
  const float* b_out   = (const float*)d_in[11];
  float* out = (float*)d_out;
  float* attn_out = out + (size_t)8 * 1024 * 512;

  const size_t oX16 = 0;
  const size_t oA2  = oX16 + 4194304;
  const size_t oWQ  = oA2  + 8388608;
  const size_t oW2  = oWQ  + 786432;
  const size_t oQP  = oW2  + 524288;
  const size_t oKP  = oQP  + 4194304;
  const size_t oVP  = oKP  + 4194304;
  const size_t oWP  = oVP  + 4194304;
  const size_t oOP  = oWP  + 4194304;          // f16 OUTP[4][8192][512]
  const size_t NEEDED = (oOP + (size_t)4 * 8192 * 512) * 2;
  if (ws_size < NEEDED) return;
  f16* ws = (f16*)d_ws;
  f16 *X16 = ws + oX16, *A2 = ws + oA2, *WQ = ws + oWQ, *W2 = ws + oW2;
  f16 *QP = ws + oQP, *KP = ws + oKP, *VP = ws + oVP, *WP = ws + oWP;
  f16* OUTP = ws + oOP;

  kprep<<<dim3(2048, 6), 256, 0, stream>>>(x, rt, rc, w_qkv, w_kr_t, w_kr_c,
                                           X16, A2, WQ, W2);
  kproj<<<dim3(64, 16), 256, 0, stream>>>(X16, A2, WQ, W2, bias_te, QP, KP, VP, WP);
  kdots<<<dim3(4, 32, 8), 512, 0, stream>>>(QP, KP, WP, VP, attn_out, OUTP);
  kout<<<dim3(64, 8), 256, 0, stream>>>(OUTP, w_out, b_out, out);
}

// Round 15
// 216.685 us; speedup vs baseline: 1.1101x; 1.1101x over previous
//
#include <hip/hip_runtime.h>
#include <hip/hip_fp16.h>

// B=8, N=1024, E=512, H=8, D=64
// ws (f16): X16[8192][512], A2[8192][1024], WQ[1536][512], W2[512][1024],
//           QP/KP/WP packed A/B-frag, VP packed, OUTP[4][8192][512] f16
// BEST-KNOWN CONFIG (round 11, 217.3us). Reverts r12-r14 experiments:
//  - kdots: transposed MFMAs, TWO-candidate predicated scatter stores (indep,
//    exec-mask cheap); single-candidate dep-chain was +13us; 128-col pair +10.
//  - kproj: reg-staging (gls serialized stage/compute: +12us).
// launch_bounds(512,4): 128-VGPR cap ((512,8) forced 32 VGPR + spills).

typedef _Float16 f16;
typedef f16 f16x4 __attribute__((ext_vector_type(4)));
typedef f16 f16x8 __attribute__((ext_vector_type(8)));
typedef float f32x4 __attribute__((ext_vector_type(4)));

#define MFMA16(a,b,c) __builtin_amdgcn_mfma_f32_16x16x32_f16((a),(b),(c),0,0,0)

static __device__ __forceinline__ size_t qpidx(int bh, int q, int d) {
  return ((((size_t)bh * 64 + (q >> 4)) * 2 + (d >> 5)) * 64 +
          ((q & 15) + (((d >> 3) & 3) << 4))) * 8 + (d & 7);
}
static __device__ __forceinline__ size_t vpidx(int bh, int d, int j) {
  return ((((size_t)bh * 4 + (d >> 4)) * 32 + (j >> 5)) * 64 +
          ((d & 15) + (((j >> 3) & 3) << 4))) * 8 + (j & 7);
}

// ---------------- Kernel 0: prep (convert + concat + transpose weights) -----
__global__ __launch_bounds__(256) void kprep(
    const float* __restrict__ x, const float* __restrict__ rt, const float* __restrict__ rc,
    const float* __restrict__ wqkv, const float* __restrict__ wkrt, const float* __restrict__ wkrc,
    f16* __restrict__ X16, f16* __restrict__ A2, f16* __restrict__ WQ, f16* __restrict__ W2)
{
  const int t = threadIdx.x, gx = blockIdx.x, mode = blockIdx.y;
  if (mode <= 2) {
    const size_t id = (size_t)gx * 256 + t;
    const float* src = (mode == 0) ? x : (mode == 1) ? rt : rc;
    float4 v0 = *(const float4*)&src[id * 8];
    float4 v1 = *(const float4*)&src[id * 8 + 4];
    f16x8 o = {(f16)v0.x, (f16)v0.y, (f16)v0.z, (f16)v0.w,
               (f16)v1.x, (f16)v1.y, (f16)v1.z, (f16)v1.w};
    if (mode == 0) *(f16x8*)&X16[id * 8] = o;
    else {
      const int mrow = (int)(id >> 6), cc = (int)(id & 63);
      *(f16x8*)&A2[(size_t)mrow * 1024 + (mode == 2 ? 512 : 0) + cc * 8] = o;
    }
  } else if (mode == 3) {
    if (gx >= 384) return;
    const int c = gx & 63, n = (gx >> 6) * 256 + t;
    f16x8 o;
    #pragma unroll
    for (int e = 0; e < 8; ++e) o[e] = (f16)wqkv[(size_t)(c * 8 + e) * 1536 + n];
    *(f16x8*)&WQ[(size_t)n * 512 + c * 8] = o;
  } else {
    if (gx >= 128) return;
    const int c = gx & 63, n = (gx >> 6) * 256 + t;
    const float* src = (mode == 4) ? wkrt : wkrc;
    f16x8 o;
    #pragma unroll
    for (int e = 0; e < 8; ++e) o[e] = (f16)src[(size_t)(c * 8 + e) * 512 + n];
    *(f16x8*)&W2[(size_t)n * 1024 + (mode == 5 ? 512 : 0) + c * 8] = o;
  }
}

// ---------------- Kernel A: projections (128x128 tile, BK=64, swizzled LDS) --
// XCD swizzle: lin%8 = m-chunk -> each XCD's A-panel stays L2-resident.
__global__ __launch_bounds__(256) void kproj(
    const f16* __restrict__ X16, const f16* __restrict__ A2,
    const f16* __restrict__ WQ, const f16* __restrict__ W2,
    const float* __restrict__ bias_te,
    f16* __restrict__ QP, f16* __restrict__ KP, f16* __restrict__ VP, f16* __restrict__ WP)
{
  __shared__ f16 As[128 * 64];
  __shared__ f16 Bs[128 * 64];
  const int t = threadIdx.x, l = t & 63, w = t >> 6;
  const int wr = w >> 1, wc = w & 1;
  const int lin = blockIdx.x + 64 * blockIdx.y;      // dispatch-linear
  const int mchunk = lin & 7;
  const int rem = lin >> 3;
  const int m0 = (mchunk * 8 + (rem & 7)) * 128;
  const int y = rem >> 3;                            // 0..15
  const int mode = y >> 2;
  const bool wrs = (mode == 3);
  const f16* Asrc = wrs ? A2 : X16;
  const int lda = wrs ? 1024 : 512;
  const int K = wrs ? 1024 : 512;
  const f16* Bsrc = wrs ? (W2 + (size_t)((y - 12) * 128) * 1024)
                        : (WQ + (size_t)(y * 128) * 512);
  const int ldb = wrs ? 1024 : 512;

  f32x4 acc[4][4] = {};
  for (int k0 = 0; k0 < K; k0 += 64) {
    __syncthreads();
    #pragma unroll
    for (int rep = 0; rep < 4; ++rep) {
      const int idx = rep * 256 + t;
      const int row = idx >> 3, kb = idx & 7;
      const int slot = (kb ^ (row & 7)) << 3;
      f16x8 va = *(const f16x8*)&Asrc[(size_t)(m0 + row) * lda + k0 + kb * 8];
      *(f16x8*)&As[row * 64 + slot] = va;
      f16x8 vb = *(const f16x8*)&Bsrc[(size_t)row * ldb + k0 + kb * 8];
      *(f16x8*)&Bs[row * 64 + slot] = vb;
    }
    __syncthreads();
    #pragma unroll
    for (int kc = 0; kc < 2; ++kc) {
      f16x8 af[4], bf[4];
      const int kb = kc * 4 + (l >> 4);
      #pragma unroll
      for (int mb = 0; mb < 4; ++mb) {
        const int r = wr * 64 + mb * 16 + (l & 15);
        af[mb] = *(const f16x8*)&As[r * 64 + ((kb ^ (r & 7)) << 3)];
      }
      #pragma unroll
      for (int nb = 0; nb < 4; ++nb) {
        const int r = wc * 64 + nb * 16 + (l & 15);
        bf[nb] = *(const f16x8*)&Bs[r * 64 + ((kb ^ (r & 7)) << 3)];
      }
      #pragma unroll
      for (int mb = 0; mb < 4; ++mb)
      #pragma unroll
      for (int nb = 0; nb < 4; ++nb)
        acc[mb][nb] = MFMA16(af[mb], bf[nb], acc[mb][nb]);
    }
  }
  #pragma unroll
  for (int mb = 0; mb < 4; ++mb)
  #pragma unroll
  for (int nb = 0; nb < 4; ++nb) {
    const int loc = wc * 64 + nb * 16 + (l & 15);
    const int c = (y & 3) * 128 + loc;
    const int hh = c >> 6, d = c & 63;
    const float badd = (mode == 0) ? bias_te[c] : 0.f;
    f32x4 a = acc[mb][nb];
    #pragma unroll
    for (int r = 0; r < 4; ++r) {
      const int m = m0 + wr * 64 + mb * 16 + (l >> 4) * 4 + r;
      const int bb = m >> 10, tn = m & 1023;
      const int bh = bb * 8 + hh;
      const float v = a[r] + badd;
      if (mode == 0)      QP[qpidx(bh, tn, d)] = (f16)v;
      else if (mode == 1) KP[qpidx(bh, tn, d)] = (f16)v;
      else if (mode == 2) VP[vpidx(bh, d, tn)] = (f16)v;
      else                WP[qpidx(bh, tn, d)] = (f16)v;
    }
  }
}

// ---- Kernel C: fused rel-shift + dots + h-softmax + attn write + PV --------
// 1024 blocks; 512 threads, wave = head. XCD swizzle: lin%8 == b.
// Per ktile: rawT scatter-STORE (two independent predicated stores) ->
// ACT f16x4 RMW-add (hole->AC) -> [sync] softmax [sync] PV. 2 barriers/ktile.
__global__ __launch_bounds__(512, 4) void kdots(
    const f16* __restrict__ QP, const f16* __restrict__ KP,
    const f16* __restrict__ WP, const f16* __restrict__ VP,
    float* __restrict__ attn_out, f16* __restrict__ OUTP)
{
  __shared__ f16 sd[8][32][72];
  const int t = threadIdx.x, l = t & 63, h = t >> 6;
  const int lin = blockIdx.x + 4 * blockIdx.y + 128 * blockIdx.z;
  const int b = lin & 7;                 // XCD j owns batch j
  const int rem = lin >> 3;
  const int kg = rem & 3;
  const int q0 = (rem >> 2) * 32;
  const int bh = b * 8 + h;
  const f16x8* QP8 = (const f16x8*)QP;
  const f16x8* KP8 = (const f16x8*)KP;
  const f16x8* WP8 = (const f16x8*)WP;
  const f16x8* VP8 = (const f16x8*)VP;
  const int qrow = (l >> 4) * 4;
  // Q fragments: rows q0..q0+47 (3rd block only contributes q=q0+32, region B)
  f16x8 aq[3][2];
  #pragma unroll
  for (int mb = 0; mb < 3; ++mb)
  #pragma unroll
  for (int kc = 0; kc < 2; ++kc)
    aq[mb][kc] = QP8[((size_t)(bh * 64 + (q0 >> 4) + mb) * 2 + kc) * 64 + l];

  f32x4 oacc[2][4] = {};   // PV accumulator across the 4 ktiles

  for (int kti = 0; kti < 4; ++kti) {
    const int k0 = (kg * 4 + kti) * 64;
    const int u0 = k0 - q0;
    // ---- rawT = WRS . QB^T (rows jj, cols q); scatter-STORE 0.5*raw into sd.
    auto rawblockT = [&](int jb) {
      f32x4 racc[3] = {};
      #pragma unroll
      for (int kc = 0; kc < 2; ++kc) {
        f16x8 wf = WP8[((size_t)(bh * 64 + jb) * 2 + kc) * 64 + l];
        #pragma unroll
        for (int qb = 0; qb < 3; ++qb)
          racc[qb] = MFMA16(wf, aq[qb][kc], racc[qb]);
      }
      #pragma unroll
      for (int qb = 0; qb < 3; ++qb) {
        const int qloc = qb * 16 + (l & 15);
        const int q = q0 + qloc;
        #pragma unroll
        for (int r = 0; r < 4; ++r) {
          const int jj = jb * 16 + qrow + r;
          const f16 v = (f16)(0.5f * racc[qb][r]);
          if (qloc < 32) {                          // region A: dest (q, q+jj-1023)
            const int kA = q + jj - 1023;
            if (kA >= k0 && kA < k0 + 64) sd[h][qloc][kA - k0] = v;
          }
          if (qloc >= 1 && qloc <= 32) {            // region B: dest (q-1, q+jj+1)
            const int kB = q + jj + 1;
            if (kB >= k0 && kB < k0 + 64) sd[h][qloc - 1][kB - k0] = v;
          }
        }
      }
    };
    {
      const int blo_e = u0 - 33, bhi_e = (u0 + 61 > 1023) ? 1023 : u0 + 61;
      if (bhi_e >= 0) {
        const int blo = (blo_e < 0 ? 0 : blo_e) >> 4, bhi = bhi_e >> 4;
        for (int jb = blo; jb <= bhi; ++jb) rawblockT(jb);
      }
      if (u0 <= 31) {
        const int alo_e = 992 + u0, ahi_e = (1086 + u0 > 1023) ? 1023 : 1086 + u0;
        const int alo = (alo_e < 0 ? 0 : alo_e) >> 4, ahi = ahi_e >> 4;
        for (int jb = alo; jb <= ahi; ++jb) rawblockT(jb);
      }
    }
    // ---- ACT = K . QB^T (rows k, cols q); vector f16x4 RMW-add into sd ----
    {
      f32x4 acc[4][2] = {};
      #pragma unroll
      for (int kc = 0; kc < 2; ++kc) {
        #pragma unroll
        for (int kb = 0; kb < 4; ++kb) {
          f16x8 kf = KP8[((size_t)(bh * 64 + (k0 >> 4) + kb) * 2 + kc) * 64 + l];
          #pragma unroll
          for (int qb = 0; qb < 2; ++qb)
            acc[kb][qb] = MFMA16(kf, aq[qb][kc], acc[kb][qb]);
        }
      }
      #pragma unroll
      for (int kb = 0; kb < 4; ++kb)
      #pragma unroll
      for (int qb = 0; qb < 2; ++qb) {
        const int qloc = qb * 16 + (l & 15);
        const int kbase = kb * 16 + qrow;            // 4-aligned local col
        const int hol = (q0 + qloc + 1) - (k0 + kbase);  // hole e in [0,3]?
        f16x4 cur = *(const f16x4*)&sd[h][qloc][kbase];
        f16x4 res;
        #pragma unroll
        for (int e = 0; e < 4; ++e) {
          const float rv = (e == hol) ? 0.f : (float)cur[e];
          res[e] = (f16)(rv + acc[kb][qb][e]);
        }
        *(f16x4*)&sd[h][qloc][kbase] = res;
      }
    }
    __syncthreads();
    // ---- softmax over heads + attn write (nontemporal) + P writeback ----
    {
      const int o = t * 4, q = o >> 6, k = o & 63;
      float dv[8][4];
      #pragma unroll
      for (int hh = 0; hh < 8; ++hh) {
        f16x4 v = *(const f16x4*)&sd[hh][q][k];
        dv[hh][0] = (float)v[0]; dv[hh][1] = (float)v[1];
        dv[hh][2] = (float)v[2]; dv[hh][3] = (float)v[3];
      }
      #pragma unroll
      for (int e = 0; e < 4; ++e) {
        float m = dv[0][e];
        #pragma unroll
        for (int hh = 1; hh < 8; ++hh) m = fmaxf(m, dv[hh][e]);
        float ssum = 0.f;
        #pragma unroll
        for (int hh = 0; hh < 8; ++hh) { float a = __expf(dv[hh][e] - m); dv[hh][e] = a; ssum += a; }
        float rinv = 1.f / ssum;
        #pragma unroll
        for (int hh = 0; hh < 8; ++hh) dv[hh][e] *= rinv;
      }
      const size_t qg = q0 + q;
      #pragma unroll
      for (int hh = 0; hh < 8; ++hh) {
        f32x4* dst = (f32x4*)&attn_out[((size_t)(b * 8 + hh) * 1024 + qg) * 1024 + k0 + k];
        __builtin_nontemporal_store(f32x4{dv[hh][0], dv[hh][1], dv[hh][2], dv[hh][3]}, dst);
        *(f16x4*)&sd[hh][q][k] =
            f16x4{(f16)dv[hh][0], (f16)dv[hh][1], (f16)dv[hh][2], (f16)dv[hh][3]};
      }
    }
    __syncthreads();
    // ---- PV: oacc[q,d] += P[q,j] * V[j,d] ----
    #pragma unroll
    for (int kc = 0; kc < 2; ++kc) {
      f16x8 pa[2];
      #pragma unroll
      for (int mb = 0; mb < 2; ++mb) {
        const int qq = mb * 16 + (l & 15);
        const int jj = kc * 32 + (l >> 4) * 8;
        pa[mb] = *(const f16x8*)&sd[h][qq][jj];
      }
      #pragma unroll
      for (int nb = 0; nb < 4; ++nb) {
        f16x8 vb = VP8[(((size_t)bh * 4 + nb) * 32 + (k0 >> 5) + kc) * 64 + l];
        #pragma unroll
        for (int mb = 0; mb < 2; ++mb)
          oacc[mb][nb] = MFMA16(pa[mb], vb, oacc[mb][nb]);
      }
    }
  }
  // ---- write PV partial (f16): OUTP[kg][b*1024+q][h*64+d] ----
  f16* op = OUTP + ((size_t)kg * 8192 + (size_t)b * 1024) * 512;
  #pragma unroll
  for (int mb = 0; mb < 2; ++mb)
  #pragma unroll
  for (int nb = 0; nb < 4; ++nb)
  #pragma unroll
  for (int r = 0; r < 4; ++r) {
    const int qg = q0 + mb * 16 + qrow + r;
    const int dd = nb * 16 + (l & 15);
    op[(size_t)qg * 512 + h * 64 + dd] = (f16)oacc[mb][nb][r];
  }
}

// ---------------- Kernel D: out = (sum_p OUTP[p]) @ w_out + b_out ----------
__global__ __launch_bounds__(256) void kout(
    const f16* __restrict__ OUTP, const float* __restrict__ w_out,
    const float* __restrict__ b_out, float* __restrict__ out)
{
  __shared__ f16 a_s[128][36];
  __shared__ f16 b_s[64][36];
  const int t = threadIdx.x, l = t & 63, w = t >> 6;
  const int m0 = blockIdx.x * 128;
  const int c0 = blockIdx.y * 64;
  f32x4 acc[2][4] = {};
  for (int k0 = 0; k0 < 512; k0 += 32) {
    __syncthreads();
    #pragma unroll
    for (int rep = 0; rep < 2; ++rep) {       // A: sum 4 f16 partials -> f16
      const int s = rep * 256 + t;            // 512 chunks of 8 (128x32)
      const int r = s >> 2, c = (s & 3) * 8;
      const size_t off = (size_t)(m0 + r) * 512 + k0 + c;
      f16x8 p0 = *(const f16x8*)&OUTP[off];
      f16x8 p1 = *(const f16x8*)&OUTP[off + 4194304];
      f16x8 p2 = *(const f16x8*)&OUTP[off + 8388608];
      f16x8 p3 = *(const f16x8*)&OUTP[off + 12582912];
      f16x4 lo, hi;
      #pragma unroll
      for (int e = 0; e < 4; ++e) {
        lo[e] = (f16)((float)p0[e] + (float)p1[e] + (float)p2[e] + (float)p3[e]);
        hi[e] = (f16)((float)p0[e+4] + (float)p1[e+4] + (float)p2[e+4] + (float)p3[e+4]);
      }
      *(f16x4*)&a_s[r][c]     = lo;
      *(f16x4*)&a_s[r][c + 4] = hi;
    }
    #pragma unroll
    for (int rep = 0; rep < 2; ++rep) {
      int idx = rep * 1024 + t * 4;
      int kr = idx >> 6, c = idx & 63;
      float4 v = *(const float4*)&w_out[(size_t)(k0 + kr) * 512 + c0 + c];
      b_s[c + 0][kr] = (f16)v.x; b_s[c + 1][kr] = (f16)v.y;
      b_s[c + 2][kr] = (f16)v.z; b_s[c + 3][kr] = (f16)v.w;
    }
    __syncthreads();
    const int kc = (l >> 4) * 8;
    f16x8 af[2];
    #pragma unroll
    for (int mb = 0; mb < 2; ++mb) {
      int r = w * 32 + mb * 16 + (l & 15);
      af[mb] = __builtin_shufflevector(*(const f16x4*)&a_s[r][kc], *(const f16x4*)&a_s[r][kc + 4],
                                       0, 1, 2, 3, 4, 5, 6, 7);
    }
    #pragma unroll
    for (int nb = 0; nb < 4; ++nb) {
      int cc = nb * 16 + (l & 15);
      f16x8 bf = __builtin_shufflevector(*(const f16x4*)&b_s[cc][kc], *(const f16x4*)&b_s[cc][kc + 4],
                                         0, 1, 2, 3, 4, 5, 6, 7);
      #pragma unroll
      for (int mb = 0; mb < 2; ++mb)
        acc[mb][nb] = MFMA16(af[mb], bf, acc[mb][nb]);
    }
  }
  #pragma unroll
  for (int mb = 0; mb < 2; ++mb)
  #pragma unroll
  for (int nb = 0; nb < 4; ++nb) {
    const int cg = c0 + nb * 16 + (l & 15);
    const float bb = b_out[cg];
    #pragma unroll
    for (int r = 0; r < 4; ++r) {
      const int m = m0 + w * 32 + mb * 16 + (l >> 4) * 4 + r;
      out[(size_t)m * 512 + cg] = acc[mb][nb][r] + bb;
    }
  }
}

extern "C" void kernel_launch(void* const* d_in, const int* in_sizes, int n_in,
                              void* d_out, int out_size, void* d_ws, size_t ws_size,
                              hipStream_t stream) {
  const float* x       = (const float*)d_in[0];
  const float* rt      = (const float*)d_in[1];
  const float* rc      = (const float*)d_in[2];
  const float* bias_te = (const float*)d_in[3];
  const float* w_qkv   = (const float*)d_in[7];
  const float* w_kr_t  = (const float*)d_in[8];
  const float* w_kr_c  = (const float*)d_in[9];
  const float* w_out   = (const float*)d_in[10];
  const float* b_out   = (const float*)d_in[11];
  float* out = (float*)d_out;
  float* attn_out = out + (size_t)8 * 1024 * 512;

  const size_t oX16 = 0;
  const size_t oA2  = oX16 + 4194304;
  const size_t oWQ  = oA2  + 8388608;
  const size_t oW2  = oWQ  + 786432;
  const size_t oQP  = oW2  + 524288;
  const size_t oKP  = oQP  + 4194304;
  const size_t oVP  = oKP  + 4194304;
  const size_t oWP  = oVP  + 4194304;
  const size_t oOP  = oWP  + 4194304;          // f16 OUTP[4][8192][512]
  const size_t NEEDED = (oOP + (size_t)4 * 8192 * 512) * 2;
  if (ws_size < NEEDED) return;
  f16* ws = (f16*)d_ws;
  f16 *X16 = ws + oX16, *A2 = ws + oA2, *WQ = ws + oWQ, *W2 = ws + oW2;
  f16 *QP = ws + oQP, *KP = ws + oKP, *VP = ws + oVP, *WP = ws + oWP;
  f16* OUTP = ws + oOP;

  kprep<<<dim3(2048, 6), 256, 0, stream>>>(x, rt, rc, w_qkv, w_kr_t, w_kr_c,
                                           X16, A2, WQ, W2);
  kproj<<<dim3(64, 16), 256, 0, stream>>>(X16, A2, WQ, W2, bias_te, QP, KP, VP, WP);
  kdots<<<dim3(4, 32, 8), 512, 0, stream>>>(QP, KP, WP, VP, attn_out, OUTP);
  kout<<<dim3(64, 8), 256, 0, stream>>>(OUTP, w_out, b_out, out);
}

// Round 16
// 215.003 us; speedup vs baseline: 1.1188x; 1.0078x over previous
//
#include <hip/hip_runtime.h>
#include <hip/hip_fp16.h>

// B=8, N=1024, E=512, H=8, D=64
// ws (f16): WQ[1536][512], W2[512][1024], QP/KP/WP packed A/B-frag, VP packed,
//           OUTP[4][8192][512] f16
// r16: kprep reduced to WEIGHT transposes only; kproj stages x/rt/rc fp32
//   directly (2xfloat4 -> cvt -> ds_write_b128). XCD swizzle keeps each XCD's
//   2MB fp32 A-chunk L2-resident, so HBM fetch ~= one pass.
// kdots: r11 best-known (transposed MFMAs, two-candidate predicated scatter,
//   2 barriers/ktile, nt attn stores, XCD swizzle lin%8==b).
// launch_bounds(512,4): 128-VGPR cap ((512,8) forced 32 VGPR + spills, r8).

typedef _Float16 f16;
typedef f16 f16x4 __attribute__((ext_vector_type(4)));
typedef f16 f16x8 __attribute__((ext_vector_type(8)));
typedef float f32x4 __attribute__((ext_vector_type(4)));

#define MFMA16(a,b,c) __builtin_amdgcn_mfma_f32_16x16x32_f16((a),(b),(c),0,0,0)

static __device__ __forceinline__ size_t qpidx(int bh, int q, int d) {
  return ((((size_t)bh * 64 + (q >> 4)) * 2 + (d >> 5)) * 64 +
          ((q & 15) + (((d >> 3) & 3) << 4))) * 8 + (d & 7);
}
static __device__ __forceinline__ size_t vpidx(int bh, int d, int j) {
  return ((((size_t)bh * 4 + (d >> 4)) * 32 + (j >> 5)) * 64 +
          ((d & 15) + (((j >> 3) & 3) << 4))) * 8 + (j & 7);
}

// -------- Kernel 0: prep (weight transposes only; activations read raw) -----
__global__ __launch_bounds__(256) void kprep(
    const float* __restrict__ wqkv, const float* __restrict__ wkrt,
    const float* __restrict__ wkrc,
    f16* __restrict__ WQ, f16* __restrict__ W2)
{
  const int t = threadIdx.x, gx = blockIdx.x, mode = blockIdx.y;
  if (mode == 0) {             // WQ[n][k] = wqkv[k][n], f16  (gx < 384)
    const int c = gx & 63, n = (gx >> 6) * 256 + t;
    f16x8 o;
    #pragma unroll
    for (int e = 0; e < 8; ++e) o[e] = (f16)wqkv[(size_t)(c * 8 + e) * 1536 + n];
    *(f16x8*)&WQ[(size_t)n * 512 + c * 8] = o;
  } else {                     // W2[n][k<512]=wkrt[k][n]; W2[n][512+k]=wkrc[k][n]
    if (gx >= 128) return;
    const int c = gx & 63, n = (gx >> 6) * 256 + t;
    const float* src = (mode == 1) ? wkrt : wkrc;
    f16x8 o;
    #pragma unroll
    for (int e = 0; e < 8; ++e) o[e] = (f16)src[(size_t)(c * 8 + e) * 512 + n];
    *(f16x8*)&W2[(size_t)n * 1024 + (mode == 2 ? 512 : 0) + c * 8] = o;
  }
}

// ---------------- Kernel A: projections (128x128 tile, BK=64, swizzled LDS) --
// XCD swizzle: lin%8 = m-chunk -> each XCD's fp32 A-chunk (2MB) L2-resident.
// A staged fp32->f16 in-flight; B (weights) staged f16.
__global__ __launch_bounds__(256) void kproj(
    const float* __restrict__ x, const float* __restrict__ rt, const float* __restrict__ rc,
    const f16* __restrict__ WQ, const f16* __restrict__ W2,
    const float* __restrict__ bias_te,
    f16* __restrict__ QP, f16* __restrict__ KP, f16* __restrict__ VP, f16* __restrict__ WP)
{
  __shared__ f16 As[128 * 64];
  __shared__ f16 Bs[128 * 64];
  const int t = threadIdx.x, l = t & 63, w = t >> 6;
  const int wr = w >> 1, wc = w & 1;
  const int lin = blockIdx.x + 64 * blockIdx.y;      // dispatch-linear
  const int mchunk = lin & 7;
  const int rem = lin >> 3;
  const int m0 = (mchunk * 8 + (rem & 7)) * 128;
  const int y = rem >> 3;                            // 0..15
  const int mode = y >> 2;
  const bool wrs = (mode == 3);
  const int K = wrs ? 1024 : 512;
  const f16* Bsrc = wrs ? (W2 + (size_t)((y - 12) * 128) * 1024)
                        : (WQ + (size_t)(y * 128) * 512);
  const int ldb = wrs ? 1024 : 512;

  f32x4 acc[4][4] = {};
  for (int k0 = 0; k0 < K; k0 += 64) {
    // fp32 A source: x for QKV; rt (k0<512) / rc (k0>=512) for WRS
    const float* A32 = wrs ? ((k0 < 512) ? rt : rc) : x;
    const int acol = wrs ? (k0 & 511) : k0;
    __syncthreads();
    #pragma unroll
    for (int rep = 0; rep < 4; ++rep) {
      const int idx = rep * 256 + t;
      const int row = idx >> 3, kb = idx & 7;
      const int slot = (kb ^ (row & 7)) << 3;
      const size_t aoff = (size_t)(m0 + row) * 512 + acol + kb * 8;
      float4 v0 = *(const float4*)&A32[aoff];
      float4 v1 = *(const float4*)&A32[aoff + 4];
      *(f16x8*)&As[row * 64 + slot] = f16x8{(f16)v0.x, (f16)v0.y, (f16)v0.z, (f16)v0.w,
                                            (f16)v1.x, (f16)v1.y, (f16)v1.z, (f16)v1.w};
      f16x8 vb = *(const f16x8*)&Bsrc[(size_t)row * ldb + k0 + kb * 8];
      *(f16x8*)&Bs[row * 64 + slot] = vb;
    }
    __syncthreads();
    #pragma unroll
    for (int kc = 0; kc < 2; ++kc) {
      f16x8 af[4], bf[4];
      const int kb = kc * 4 + (l >> 4);
      #pragma unroll
      for (int mb = 0; mb < 4; ++mb) {
        const int r = wr * 64 + mb * 16 + (l & 15);
        af[mb] = *(const f16x8*)&As[r * 64 + ((kb ^ (r & 7)) << 3)];
      }
      #pragma unroll
      for (int nb = 0; nb < 4; ++nb) {
        const int r = wc * 64 + nb * 16 + (l & 15);
        bf[nb] = *(const f16x8*)&Bs[r * 64 + ((kb ^ (r & 7)) << 3)];
      }
      #pragma unroll
      for (int mb = 0; mb < 4; ++mb)
      #pragma unroll
      for (int nb = 0; nb < 4; ++nb)
        acc[mb][nb] = MFMA16(af[mb], bf[nb], acc[mb][nb]);
    }
  }
  #pragma unroll
  for (int mb = 0; mb < 4; ++mb)
  #pragma unroll
  for (int nb = 0; nb < 4; ++nb) {
    const int loc = wc * 64 + nb * 16 + (l & 15);
    const int c = (y & 3) * 128 + loc;
    const int hh = c >> 6, d = c & 63;
    const float badd = (mode == 0) ? bias_te[c] : 0.f;
    f32x4 a = acc[mb][nb];
    #pragma unroll
    for (int r = 0; r < 4; ++r) {
      const int m = m0 + wr * 64 + mb * 16 + (l >> 4) * 4 + r;
      const int bb = m >> 10, tn = m & 1023;
      const int bh = bb * 8 + hh;
      const float v = a[r] + badd;
      if (mode == 0)      QP[qpidx(bh, tn, d)] = (f16)v;
      else if (mode == 1) KP[qpidx(bh, tn, d)] = (f16)v;
      else if (mode == 2) VP[vpidx(bh, d, tn)] = (f16)v;
      else                WP[qpidx(bh, tn, d)] = (f16)v;
    }
  }
}

// ---- Kernel C: fused rel-shift + dots + h-softmax + attn write + PV --------
// 1024 blocks; 512 threads, wave = head. XCD swizzle: lin%8 == b.
// Per ktile: rawT scatter-STORE (two independent predicated stores) ->
// ACT f16x4 RMW-add (hole->AC) -> [sync] softmax [sync] PV. 2 barriers/ktile.
__global__ __launch_bounds__(512, 4) void kdots(
    const f16* __restrict__ QP, const f16* __restrict__ KP,
    const f16* __restrict__ WP, const f16* __restrict__ VP,
    float* __restrict__ attn_out, f16* __restrict__ OUTP)
{
  __shared__ f16 sd[8][32][72];
  const int t = threadIdx.x, l = t & 63, h = t >> 6;
  const int lin = blockIdx.x + 4 * blockIdx.y + 128 * blockIdx.z;
  const int b = lin & 7;                 // XCD j owns batch j
  const int rem = lin >> 3;
  const int kg = rem & 3;
  const int q0 = (rem >> 2) * 32;
  const int bh = b * 8 + h;
  const f16x8* QP8 = (const f16x8*)QP;
  const f16x8* KP8 = (const f16x8*)KP;
  const f16x8* WP8 = (const f16x8*)WP;
  const f16x8* VP8 = (const f16x8*)VP;
  const int qrow = (l >> 4) * 4;
  // Q fragments: rows q0..q0+47 (3rd block only contributes q=q0+32, region B)
  f16x8 aq[3][2];
  #pragma unroll
  for (int mb = 0; mb < 3; ++mb)
  #pragma unroll
  for (int kc = 0; kc < 2; ++kc)
    aq[mb][kc] = QP8[((size_t)(bh * 64 + (q0 >> 4) + mb) * 2 + kc) * 64 + l];

  f32x4 oacc[2][4] = {};   // PV accumulator across the 4 ktiles

  for (int kti = 0; kti < 4; ++kti) {
    const int k0 = (kg * 4 + kti) * 64;
    const int u0 = k0 - q0;
    // ---- rawT = WRS . QB^T (rows jj, cols q); scatter-STORE 0.5*raw into sd.
    auto rawblockT = [&](int jb) {
      f32x4 racc[3] = {};
      #pragma unroll
      for (int kc = 0; kc < 2; ++kc) {
        f16x8 wf = WP8[((size_t)(bh * 64 + jb) * 2 + kc) * 64 + l];
        #pragma unroll
        for (int qb = 0; qb < 3; ++qb)
          racc[qb] = MFMA16(wf, aq[qb][kc], racc[qb]);
      }
      #pragma unroll
      for (int qb = 0; qb < 3; ++qb) {
        const int qloc = qb * 16 + (l & 15);
        const int q = q0 + qloc;
        #pragma unroll
        for (int r = 0; r < 4; ++r) {
          const int jj = jb * 16 + qrow + r;
          const f16 v = (f16)(0.5f * racc[qb][r]);
          if (qloc < 32) {                          // region A: dest (q, q+jj-1023)
            const int kA = q + jj - 1023;
            if (kA >= k0 && kA < k0 + 64) sd[h][qloc][kA - k0] = v;
          }
          if (qloc >= 1 && qloc <= 32) {            // region B: dest (q-1, q+jj+1)
            const int kB = q + jj + 1;
            if (kB >= k0 && kB < k0 + 64) sd[h][qloc - 1][kB - k0] = v;
          }
        }
      }
    };
    {
      const int blo_e = u0 - 33, bhi_e = (u0 + 61 > 1023) ? 1023 : u0 + 61;
      if (bhi_e >= 0) {
        const int blo = (blo_e < 0 ? 0 : blo_e) >> 4, bhi = bhi_e >> 4;
        for (int jb = blo; jb <= bhi; ++jb) rawblockT(jb);
      }
      if (u0 <= 31) {
        const int alo_e = 992 + u0, ahi_e = (1086 + u0 > 1023) ? 1023 : 1086 + u0;
        const int alo = (alo_e < 0 ? 0 : alo_e) >> 4, ahi = ahi_e >> 4;
        for (int jb = alo; jb <= ahi; ++jb) rawblockT(jb);
      }
    }
    // ---- ACT = K . QB^T (rows k, cols q); vector f16x4 RMW-add into sd ----
    {
      f32x4 acc[4][2] = {};
      #pragma unroll
      for (int kc = 0; kc < 2; ++kc) {
        #pragma unroll
        for (int kb = 0; kb < 4; ++kb) {
          f16x8 kf = KP8[((size_t)(bh * 64 + (k0 >> 4) + kb) * 2 + kc) * 64 + l];
          #pragma unroll
          for (int qb = 0; qb < 2; ++qb)
            acc[kb][qb] = MFMA16(kf, aq[qb][kc], acc[kb][qb]);
        }
      }
      #pragma unroll
      for (int kb = 0; kb < 4; ++kb)
      #pragma unroll
      for (int qb = 0; qb < 2; ++qb) {
        const int qloc = qb * 16 + (l & 15);
        const int kbase = kb * 16 + qrow;            // 4-aligned local col
        const int hol = (q0 + qloc + 1) - (k0 + kbase);  // hole e in [0,3]?
        f16x4 cur = *(const f16x4*)&sd[h][qloc][kbase];
        f16x4 res;
        #pragma unroll
        for (int e = 0; e < 4; ++e) {
          const float rv = (e == hol) ? 0.f : (float)cur[e];
          res[e] = (f16)(rv + acc[kb][qb][e]);
        }
        *(f16x4*)&sd[h][qloc][kbase] = res;
      }
    }
    __syncthreads();
    // ---- softmax over heads + attn write (nontemporal) + P writeback ----
    {
      const int o = t * 4, q = o >> 6, k = o & 63;
      float dv[8][4];
      #pragma unroll
      for (int hh = 0; hh < 8; ++hh) {
        f16x4 v = *(const f16x4*)&sd[hh][q][k];
        dv[hh][0] = (float)v[0]; dv[hh][1] = (float)v[1];
        dv[hh][2] = (float)v[2]; dv[hh][3] = (float)v[3];
      }
      #pragma unroll
      for (int e = 0; e < 4; ++e) {
        float m = dv[0][e];
        #pragma unroll
        for (int hh = 1; hh < 8; ++hh) m = fmaxf(m, dv[hh][e]);
        float ssum = 0.f;
        #pragma unroll
        for (int hh = 0; hh < 8; ++hh) { float a = __expf(dv[hh][e] - m); dv[hh][e] = a; ssum += a; }
        float rinv = 1.f / ssum;
        #pragma unroll
        for (int hh = 0; hh < 8; ++hh) dv[hh][e] *= rinv;
      }
      const size_t qg = q0 + q;
      #pragma unroll
      for (int hh = 0; hh < 8; ++hh) {
        f32x4* dst = (f32x4*)&attn_out[((size_t)(b * 8 + hh) * 1024 + qg) * 1024 + k0 + k];
        __builtin_nontemporal_store(f32x4{dv[hh][0], dv[hh][1], dv[hh][2], dv[hh][3]}, dst);
        *(f16x4*)&sd[hh][q][k] =
            f16x4{(f16)dv[hh][0], (f16)dv[hh][1], (f16)dv[hh][2], (f16)dv[hh][3]};
      }
    }
    __syncthreads();
    // ---- PV: oacc[q,d] += P[q,j] * V[j,d] ----
    #pragma unroll
    for (int kc = 0; kc < 2; ++kc) {
      f16x8 pa[2];
      #pragma unroll
      for (int mb = 0; mb < 2; ++mb) {
        const int qq = mb * 16 + (l & 15);
        const int jj = kc * 32 + (l >> 4) * 8;
        pa[mb] = *(const f16x8*)&sd[h][qq][jj];
      }
      #pragma unroll
      for (int nb = 0; nb < 4; ++nb) {
        f16x8 vb = VP8[(((size_t)bh * 4 + nb) * 32 + (k0 >> 5) + kc) * 64 + l];
        #pragma unroll
        for (int mb = 0; mb < 2; ++mb)
          oacc[mb][nb] = MFMA16(pa[mb], vb, oacc[mb][nb]);
      }
    }
  }
  // ---- write PV partial (f16): OUTP[kg][b*1024+q][h*64+d] ----
  f16* op = OUTP + ((size_t)kg * 8192 + (size_t)b * 1024) * 512;
  #pragma unroll
  for (int mb = 0; mb < 2; ++mb)
  #pragma unroll
  for (int nb = 0; nb < 4; ++nb)
  #pragma unroll
  for (int r = 0; r < 4; ++r) {
    const int qg = q0 + mb * 16 + qrow + r;
    const int dd = nb * 16 + (l & 15);
    op[(size_t)qg * 512 + h * 64 + dd] = (f16)oacc[mb][nb][r];
  }
}

// ---------------- Kernel D: out = (sum_p OUTP[p]) @ w_out + b_out ----------
__global__ __launch_bounds__(256) void kout(
    const f16* __restrict__ OUTP, const float* __restrict__ w_out,
    const float* __restrict__ b_out, float* __restrict__ out)
{
  __shared__ f16 a_s[128][36];
  __shared__ f16 b_s[64][36];
  const int t = threadIdx.x, l = t & 63, w = t >> 6;
  const int m0 = blockIdx.x * 128;
  const int c0 = blockIdx.y * 64;
  f32x4 acc[2][4] = {};
  for (int k0 = 0; k0 < 512; k0 += 32) {
    __syncthreads();
    #pragma unroll
    for (int rep = 0; rep < 2; ++rep) {       // A: sum 4 f16 partials -> f16
      const int s = rep * 256 + t;            // 512 chunks of 8 (128x32)
      const int r = s >> 2, c = (s & 3) * 8;
      const size_t off = (size_t)(m0 + r) * 512 + k0 + c;
      f16x8 p0 = *(const f16x8*)&OUTP[off];
      f16x8 p1 = *(const f16x8*)&OUTP[off + 4194304];
      f16x8 p2 = *(const f16x8*)&OUTP[off + 8388608];
      f16x8 p3 = *(const f16x8*)&OUTP[off + 12582912];
      f16x4 lo, hi;
      #pragma unroll
      for (int e = 0; e < 4; ++e) {
        lo[e] = (f16)((float)p0[e] + (float)p1[e] + (float)p2[e] + (float)p3[e]);
        hi[e] = (f16)((float)p0[e+4] + (float)p1[e+4] + (float)p2[e+4] + (float)p3[e+4]);
      }
      *(f16x4*)&a_s[r][c]     = lo;
      *(f16x4*)&a_s[r][c + 4] = hi;
    }
    #pragma unroll
    for (int rep = 0; rep < 2; ++rep) {
      int idx = rep * 1024 + t * 4;
      int kr = idx >> 6, c = idx & 63;
      float4 v = *(const float4*)&w_out[(size_t)(k0 + kr) * 512 + c0 + c];
      b_s[c + 0][kr] = (f16)v.x; b_s[c + 1][kr] = (f16)v.y;
      b_s[c + 2][kr] = (f16)v.z; b_s[c + 3][kr] = (f16)v.w;
    }
    __syncthreads();
    const int kc = (l >> 4) * 8;
    f16x8 af[2];
    #pragma unroll
    for (int mb = 0; mb < 2; ++mb) {
      int r = w * 32 + mb * 16 + (l & 15);
      af[mb] = __builtin_shufflevector(*(const f16x4*)&a_s[r][kc], *(const f16x4*)&a_s[r][kc + 4],
                                       0, 1, 2, 3, 4, 5, 6, 7);
    }
    #pragma unroll
    for (int nb = 0; nb < 4; ++nb) {
      int cc = nb * 16 + (l & 15);
      f16x8 bf = __builtin_shufflevector(*(const f16x4*)&b_s[cc][kc], *(const f16x4*)&b_s[cc][kc + 4],
                                         0, 1, 2, 3, 4, 5, 6, 7);
      #pragma unroll
      for (int mb = 0; mb < 2; ++mb)
        acc[mb][nb] = MFMA16(af[mb], bf, acc[mb][nb]);
    }
  }
  #pragma unroll
  for (int mb = 0; mb < 2; ++mb)
  #pragma unroll
  for (int nb = 0; nb < 4; ++nb) {
    const int cg = c0 + nb * 16 + (l & 15);
    const float bb = b_out[cg];
    #pragma unroll
    for (int r = 0; r < 4; ++r) {
      const int m = m0 + w * 32 + mb * 16 + (l >> 4) * 4 + r;
      out[(size_t)m * 512 + cg] = acc[mb][nb][r] + bb;
    }
  }
}

extern "C" void kernel_launch(void* const* d_in, const int* in_sizes, int n_in,
                              void* d_out, int out_size, void* d_ws, size_t ws_size,
                              hipStream_t stream) {
  const float* x       = (const float*)d_in[0];
  const float* rt      = (const float*)d_in[1];
  const float* rc      = (const float*)d_in[2];
  const float* bias_te = (const float*)d_in[3];
  const float* w_qkv   = (const float*)d_in[7];
  const float* w_kr_t  = (const float*)d_in[8];
  const float* w_kr_c  = (const float*)d_in[9];
  const float* w_out   = (const float*)d_in[10];
  const float* b_out   = (const float*)d_in[11];
  float* out = (float*)d_out;
  float* attn_out = out + (size_t)8 * 1024 * 512;

  const size_t oWQ  = 0;
  const size_t oW2  = oWQ  + 786432;
  const size_t oQP  = oW2  + 524288;
  const size_t oKP  = oQP  + 4194304;
  const size_t oVP  = oKP  + 4194304;
  const size_t oWP  = oVP  + 4194304;
  const size_t oOP  = oWP  + 4194304;          // f16 OUTP[4][8192][512]
  const size_t NEEDED = (oOP + (size_t)4 * 8192 * 512) * 2;
  if (ws_size < NEEDED) return;
  f16* ws = (f16*)d_ws;
  f16 *WQ = ws + oWQ, *W2 = ws + oW2;
  f16 *QP = ws + oQP, *KP = ws + oKP, *VP = ws + oVP, *WP = ws + oWP;
  f16* OUTP = ws + oOP;

  kprep<<<dim3(384, 3), 256, 0, stream>>>(w_qkv, w_kr_t, w_kr_c, WQ, W2);
  kproj<<<dim3(64, 16), 256, 0, stream>>>(x, rt, rc, WQ, W2, bias_te, QP, KP, VP, WP);
  kdots<<<dim3(4, 32, 8), 512, 0, stream>>>(QP, KP, WP, VP, attn_out, OUTP);
  kout<<<dim3(64, 8), 256, 0, stream>>>(OUTP, w_out, b_out, out);
}